// Round 3
// baseline (390.593 us; speedup 1.0000x reference)
//
#include <hip/hip_runtime.h>
#include <hip/hip_bf16.h>

// ---------------------------------------------------------------------------
// AttentionMIL: x[16,4096,1024] -> Linear+LN+ReLU -> Linear+LN+ReLU ->
//               attention (tanh linear -> scalar -> softmax over N) ->
//               weighted pool -> 2-layer classifier -> logits [16,2]
// ---------------------------------------------------------------------------

#define MTOT   65536
#define DDIM   1024
#define HDIM   512
#define NBAG   16
#define NINST  4096

typedef __attribute__((ext_vector_type(8))) short bf16x8;
typedef __attribute__((ext_vector_type(4))) float f32x4;

__device__ __forceinline__ unsigned short f2bf(float f) {
  __hip_bfloat16 h = __float2bfloat16(f);
  unsigned short u;
  __builtin_memcpy(&u, &h, 2);
  return u;
}
__device__ __forceinline__ float bf2f(unsigned short u) {
  unsigned int x = ((unsigned int)u) << 16;
  float f;
  __builtin_memcpy(&f, &x, 4);
  return f;
}

__device__ __forceinline__ void gload16(const void* g, void* l) {
  __builtin_amdgcn_global_load_lds(
      (const __attribute__((address_space(1))) unsigned int*)g,
      (__attribute__((address_space(3))) unsigned int*)l, 16, 0, 0);
}

__device__ __forceinline__ bf16x8 pack8(float4 a, float4 b) {
  bf16x8 r;
  r[0] = (short)f2bf(a.x); r[1] = (short)f2bf(a.y);
  r[2] = (short)f2bf(a.z); r[3] = (short)f2bf(a.w);
  r[4] = (short)f2bf(b.x); r[5] = (short)f2bf(b.y);
  r[6] = (short)f2bf(b.z); r[7] = (short)f2bf(b.w);
  return r;
}

#define VMW(N) asm volatile("s_waitcnt vmcnt(" #N ")" ::: "memory")
#define LKW0   asm volatile("s_waitcnt lgkmcnt(0)" ::: "memory")

// ---------------------------------------------------------------------------
// transpose + cast f32 [R][C] -> bf16 [C][R]
// ---------------------------------------------------------------------------
__global__ void transpose_cast(const float* __restrict__ src,
                               __hip_bfloat16* __restrict__ dst,
                               int R, int C) {
  __shared__ float t[32][33];
  const int c0 = blockIdx.x * 32, r0 = blockIdx.y * 32;
  const int tx = threadIdx.x, ty = threadIdx.y;  // 32 x 8
#pragma unroll
  for (int i = 0; i < 32; i += 8)
    t[ty + i][tx] = src[(size_t)(r0 + ty + i) * C + c0 + tx];
  __syncthreads();
#pragma unroll
  for (int i = 0; i < 32; i += 8)
    dst[(size_t)(c0 + ty + i) * R + r0 + tx] = __float2bfloat16(t[tx][ty + i]);
}

// ---------------------------------------------------------------------------
// Fused GEMM: out = A[M x KD] * BT^T    (BT = W^T, [512][KD] row-major)
// MODE 0: relu(LN(y+bias, g, b)) -> bf16      MODE 1: tanh(y+bias).wa2 -> f32
// Tile 128 x 512 (full width so LN fuses), BK=32, 8 waves (2M x 4N),
// wave tile 64x128. Phased schedule: B 4-deep ring staged 2 K-steps ahead
// (gload_lds), A 2-deep (gload_lds or f32-reg 2 ahead + cvt). Counted vmcnt
// (never 0 in main loop), raw s_barrier phases, setprio(1) MFMA clusters.
// XOR swizzle: 16B slot ^= row&3 (4 slots/row at BK=32), source pre-swizzled.
// ---------------------------------------------------------------------------
#define BM 128
#define BK 32

template <int KD, bool AF32, int MODE>
__global__ __launch_bounds__(512, 2)
void gemm_fused(const void* Ap, const __hip_bfloat16* __restrict__ BT,
                const float* __restrict__ bias, const float* __restrict__ gg,
                const float* __restrict__ bb, const float* __restrict__ wa2,
                const float* __restrict__ ba2, __hip_bfloat16* __restrict__ outh,
                float* __restrict__ outs) {
  __shared__ __hip_bfloat16 At[2][BM * BK];    // 2 x 8 KB
  __shared__ __hip_bfloat16 Bt[4][HDIM * BK];  // 4 x 32 KB
  __shared__ float redS[BM][4];
  __shared__ float redQ[BM][4];
  __shared__ float muL[BM];
  __shared__ float rsL[BM];

  const int tid  = threadIdx.x;
  const int lane = tid & 63;
  const int w    = tid >> 6;
  const int wm   = w >> 2;      // 0..1
  const int wn   = w & 3;       // 0..3
  const int l16  = lane & 15;
  const int lg   = lane >> 4;   // 0..3
  const size_t row0 = (size_t)blockIdx.x * BM;

  const int sr = tid >> 2;      // staging row 0..127
  const int sp = tid & 3;       // physical 16B slot 0..3
  const int slogA = sp ^ (sr & 3);

  constexpr int NT = KD / BK;   // 32 (GEMM1) or 16 (GEMM2/3); multiple of 4
  const __hip_bfloat16* Abf = (const __hip_bfloat16*)Ap;
  const float* Af32 = (const float*)Ap;

  f32x4 acc[4][8];
#pragma unroll
  for (int i = 0; i < 4; i++)
#pragma unroll
    for (int j = 0; j < 8; j++) acc[i][j] = (f32x4){0.f, 0.f, 0.f, 0.f};

  // ---- staging helpers ----
  auto issueB2 = [&](int kb, int buf, int half) {
#pragma unroll
    for (int i = 0; i < 2; i++) {
      const int row = (half * 2 + i) * 128 + sr;
      const int slog = sp ^ (row & 3);
      gload16(BT + (size_t)row * KD + kb + slog * 8, &Bt[buf][row * BK + sp * 8]);
    }
  };
  auto issueA_g = [&](int kb, int buf) {
    gload16(Abf + (row0 + sr) * KD + kb + slogA * 8, &At[buf][sr * BK + sp * 8]);
  };

  float4 fr0a, fr0b, fr1a, fr1b;  // f32 A-staging regs, two named sets
#define LOADA(FR, TT)                                                          \
  { const float* gp_ = Af32 + (row0 + sr) * KD + (TT) * BK + slogA * 8;        \
    FR##a = *reinterpret_cast<const float4*>(gp_);                             \
    FR##b = *reinterpret_cast<const float4*>(gp_ + 4); }
#define CVTA(FR, BUF)                                                          \
  { *reinterpret_cast<bf16x8*>(&At[(BUF)][sr * BK + sp * 8]) =                 \
        pack8(FR##a, FR##b); }

#define MFMA_HALF(FN0)                                                         \
  _Pragma("unroll") for (int fm = 0; fm < 4; fm++)                             \
  _Pragma("unroll") for (int fn = (FN0); fn < (FN0) + 4; fn++)                 \
      acc[fm][fn] = __builtin_amdgcn_mfma_f32_16x16x32_bf16(                   \
          af[fm], bfr[fn], acc[fm][fn], 0, 0, 0);

  // ---- prologue ----
  if constexpr (AF32) {
    LOADA(fr0, 0); VMW(0); CVTA(fr0, 0);       // A(0) -> At[0]
    issueB2(0, 0, 0); issueB2(0, 0, 1);        // B(0) -> Bt[0]
    LOADA(fr1, 1);                             // A(1) regs (cvt at t=0 P1)
    issueB2(BK, 1, 0); issueB2(BK, 1, 1);      // B(1) -> Bt[1]
    LKW0;
    __builtin_amdgcn_s_barrier();
  } else {
    issueA_g(0, 0);                            // A(0) -> At[0]
    issueB2(0, 0, 0); issueB2(0, 0, 1);        // B(0) -> Bt[0]
    issueB2(BK, 1, 0); issueB2(BK, 1, 1);      // B(1) -> Bt[1]
    __builtin_amdgcn_s_barrier();
  }

  // ---- main loop: 2 phases/step, counted vmcnt, ring buffers ----
  // steady-state issue order per step t:
  //  P0: [AF32: Areg(t+2)x2 | g23: Agl(t+1)x1], Bgl(t+2)x2
  //  P1: Bgl(t+2)x2, [AF32: vmcnt(10); cvt A(t+1); ds_write]
  // step-start wait: AF32 vmcnt(6) / g23 vmcnt(4)  => A(t),B(t) landed.
#define GSTEP(J)                                                               \
  {                                                                            \
    const int t = tb + (J);                                                    \
    if constexpr (AF32) { VMW(6); } else { VMW(4); }                           \
    bf16x8 af[4], bfr[8];                                                      \
    _Pragma("unroll") for (int fm = 0; fm < 4; fm++) {                         \
      const int row = wm * 64 + fm * 16 + l16;                                 \
      af[fm] = *reinterpret_cast<const bf16x8*>(                               \
          &At[(J) & 1][row * BK + (lg ^ (row & 3)) * 8]);                      \
    }                                                                          \
    _Pragma("unroll") for (int fn = 0; fn < 4; fn++) {                         \
      const int row = wn * 128 + fn * 16 + l16;                                \
      bfr[fn] = *reinterpret_cast<const bf16x8*>(                              \
          &Bt[(J) & 3][row * BK + (lg ^ (row & 3)) * 8]);                      \
    }                                                                          \
    if constexpr (AF32) {                                                      \
      if (t + 2 < NT) {                                                        \
        if constexpr (((J) & 1) == 0) { LOADA(fr0, t + 2); }                   \
        else                          { LOADA(fr1, t + 2); }                   \
      }                                                                        \
    } else {                                                                   \
      if (t + 1 < NT) issueA_g((t + 1) * BK, ((J) + 1) & 1);                   \
    }                                                                          \
    if (t + 2 < NT) issueB2((t + 2) * BK, ((J) + 2) & 3, 0);                   \
    __builtin_amdgcn_s_barrier();                                              \
    LKW0; __builtin_amdgcn_sched_barrier(0);                                   \
    __builtin_amdgcn_s_setprio(1);                                             \
    MFMA_HALF(0)                                                               \
    __builtin_amdgcn_s_setprio(0);                                             \
    __builtin_amdgcn_s_barrier();                                              \
    _Pragma("unroll") for (int fn = 4; fn < 8; fn++) {                         \
      const int row = wn * 128 + fn * 16 + l16;                                \
      bfr[fn] = *reinterpret_cast<const bf16x8*>(                              \
          &Bt[(J) & 3][row * BK + (lg ^ (row & 3)) * 8]);                      \
    }                                                                          \
    if (t + 2 < NT) issueB2((t + 2) * BK, ((J) + 2) & 3, 1);                   \
    if constexpr (AF32) {                                                      \
      if (t + 1 < NT) {                                                        \
        VMW(10);                                                               \
        if constexpr (((J) & 1) == 0) { CVTA(fr1, ((J) + 1) & 1); }            \
        else                          { CVTA(fr0, ((J) + 1) & 1); }            \
        LKW0;                                                                  \
      }                                                                        \
    }                                                                          \
    __builtin_amdgcn_s_barrier();                                              \
    LKW0; __builtin_amdgcn_sched_barrier(0);                                   \
    __builtin_amdgcn_s_setprio(1);                                             \
    MFMA_HALF(4)                                                               \
    __builtin_amdgcn_s_setprio(0);                                             \
    __builtin_amdgcn_s_barrier();                                              \
  }

  for (int tb = 0; tb < NT; tb += 4) {
    GSTEP(0)
    GSTEP(1)
    GSTEP(2)
    GSTEP(3)
  }
#undef GSTEP
#undef LOADA
#undef CVTA
#undef MFMA_HALF

  // ---------------- epilogue ----------------
  float biasv[8];
#pragma unroll
  for (int fn = 0; fn < 8; fn++) biasv[fn] = bias[wn * 128 + fn * 16 + l16];

  if (MODE == 0) {
    float gv[8], bv[8];
#pragma unroll
    for (int fn = 0; fn < 8; fn++) {
      const int col = wn * 128 + fn * 16 + l16;
      gv[fn] = gg[col];
      bv[fn] = bb[col];
    }
#pragma unroll
    for (int fm = 0; fm < 4; fm++)
#pragma unroll
      for (int r = 0; r < 4; r++) {
        float s1 = 0.f, s2 = 0.f;
#pragma unroll
        for (int fn = 0; fn < 8; fn++) {
          const float v = acc[fm][fn][r] + biasv[fn];
          s1 += v;
          s2 += v * v;
        }
#pragma unroll
        for (int m = 1; m < 16; m <<= 1) {
          s1 += __shfl_xor(s1, m);
          s2 += __shfl_xor(s2, m);
        }
        if (l16 == 0) {
          const int rl = wm * 64 + fm * 16 + lg * 4 + r;
          redS[rl][wn] = s1;
          redQ[rl][wn] = s2;
        }
      }
    __syncthreads();
    if (tid < BM) {
      const float S = redS[tid][0] + redS[tid][1] + redS[tid][2] + redS[tid][3];
      const float Q = redQ[tid][0] + redQ[tid][1] + redQ[tid][2] + redQ[tid][3];
      const float mean = S * (1.f / 512.f);
      const float var = Q * (1.f / 512.f) - mean * mean;
      muL[tid] = mean;
      rsL[tid] = rsqrtf(var + 1e-5f);
    }
    __syncthreads();
#pragma unroll
    for (int fm = 0; fm < 4; fm++)
#pragma unroll
      for (int r = 0; r < 4; r++) {
        const int rl = wm * 64 + fm * 16 + lg * 4 + r;
        const float mu = muL[rl], rs = rsL[rl];
#pragma unroll
        for (int fn = 0; fn < 8; fn++) {
          const float v = acc[fm][fn][r] + biasv[fn];
          float y = (v - mu) * rs * gv[fn] + bv[fn];
          y = fmaxf(y, 0.f);
          outh[(row0 + rl) * HDIM + wn * 128 + fn * 16 + l16] =
              __float2bfloat16(y);
        }
      }
  } else {
    float wv[8];
#pragma unroll
    for (int fn = 0; fn < 8; fn++) wv[fn] = wa2[wn * 128 + fn * 16 + l16];
#pragma unroll
    for (int fm = 0; fm < 4; fm++)
#pragma unroll
      for (int r = 0; r < 4; r++) {
        float s = 0.f;
#pragma unroll
        for (int fn = 0; fn < 8; fn++) {
          const float v = acc[fm][fn][r] + biasv[fn];
          s += tanhf(v) * wv[fn];
        }
#pragma unroll
        for (int m = 1; m < 16; m <<= 1) s += __shfl_xor(s, m);
        if (l16 == 0) redS[wm * 64 + fm * 16 + lg * 4 + r][wn] = s;
      }
    __syncthreads();
    if (tid < BM) {
      outs[row0 + tid] =
          redS[tid][0] + redS[tid][1] + redS[tid][2] + redS[tid][3] + ba2[0];
    }
  }
}

// ---------------------------------------------------------------------------
// softmax over 4096 instances per bag
// ---------------------------------------------------------------------------
__global__ void softmax_bag(const float* __restrict__ sc, float* __restrict__ at) {
  const int b = blockIdx.x;
  const int tid = threadIdx.x;  // 256
  const int lane = tid & 63, w = tid >> 6;
  const float* s = sc + (size_t)b * NINST;
  float v[16];
  float mx = -1e30f;
#pragma unroll
  for (int i = 0; i < 16; i++) {
    v[i] = s[tid + i * 256];
    mx = fmaxf(mx, v[i]);
  }
#pragma unroll
  for (int off = 32; off; off >>= 1) mx = fmaxf(mx, __shfl_xor(mx, off));
  __shared__ float red[4];
  if (lane == 0) red[w] = mx;
  __syncthreads();
  mx = fmaxf(fmaxf(red[0], red[1]), fmaxf(red[2], red[3]));
  float sum = 0.f;
#pragma unroll
  for (int i = 0; i < 16; i++) {
    v[i] = expf(v[i] - mx);
    sum += v[i];
  }
#pragma unroll
  for (int off = 32; off; off >>= 1) sum += __shfl_xor(sum, off);
  __shared__ float red2[4];
  if (lane == 0) red2[w] = sum;
  __syncthreads();
  sum = red2[0] + red2[1] + red2[2] + red2[3];
  const float inv = 1.f / sum;
#pragma unroll
  for (int i = 0; i < 16; i++) at[(size_t)b * NINST + tid + i * 256] = v[i] * inv;
}

// ---------------------------------------------------------------------------
// pooled[b,h] = sum_n attn[b,n] * h2[b,n,h]
// ---------------------------------------------------------------------------
__global__ void pooled_partial(const __hip_bfloat16* __restrict__ h2,
                               const float* __restrict__ at,
                               float* __restrict__ part) {
  const int bid = blockIdx.x;
  const int b = bid >> 5, cc = (bid >> 3) & 3, nch = bid & 7;
  const int tid = threadIdx.x;  // 256
  const int c4 = (tid & 31) * 4, sub = tid >> 5;
  const int n0 = nch * 512;
  const size_t base = (size_t)b * NINST;
  float a0 = 0.f, a1 = 0.f, a2 = 0.f, a3 = 0.f;
  for (int n = n0 + sub; n < n0 + 512; n += 8) {
    const float a = at[base + n];
    const ushort4 u = *reinterpret_cast<const ushort4*>(
        &h2[(base + n) * HDIM + cc * 128 + c4]);
    a0 += a * bf2f(u.x);
    a1 += a * bf2f(u.y);
    a2 += a * bf2f(u.z);
    a3 += a * bf2f(u.w);
  }
  __shared__ float pb[8][128];
  pb[sub][c4 + 0] = a0;
  pb[sub][c4 + 1] = a1;
  pb[sub][c4 + 2] = a2;
  pb[sub][c4 + 3] = a3;
  __syncthreads();
  if (tid < 128) {
    float s = 0.f;
#pragma unroll
    for (int j = 0; j < 8; j++) s += pb[j][tid];
    part[(size_t)nch * 8192 + b * 512 + cc * 128 + tid] = s;
  }
}

__global__ void pooled_reduce(const float* __restrict__ part,
                              float* __restrict__ pooled) {
  const int i = blockIdx.x * 256 + threadIdx.x;  // 8192 total
  float s = 0.f;
#pragma unroll
  for (int j = 0; j < 8; j++) s += part[(size_t)j * 8192 + i];
  pooled[i] = s;
}

// ---------------------------------------------------------------------------
// classifier
// ---------------------------------------------------------------------------
__global__ void classifier(const float* __restrict__ pooled,
                           const float* __restrict__ Wc1,
                           const float* __restrict__ bc1,
                           const float* __restrict__ Wc2,
                           const float* __restrict__ bc2,
                           float* __restrict__ out) {
  __shared__ float P[NBAG][512];
  __shared__ float Rb[NBAG][512];
  const int tid = threadIdx.x;  // 512
#pragma unroll
  for (int i = 0; i < NBAG; i++) P[i][tid] = pooled[i * 512 + tid];
  __syncthreads();
  float r[NBAG];
#pragma unroll
  for (int i = 0; i < NBAG; i++) r[i] = 0.f;
  for (int k = 0; k < 512; k++) {
    const float wv = Wc1[k * 512 + tid];
#pragma unroll
    for (int i = 0; i < NBAG; i++) r[i] += P[i][k] * wv;
  }
#pragma unroll
  for (int i = 0; i < NBAG; i++) Rb[i][tid] = fmaxf(r[i] + bc1[tid], 0.f);
  __syncthreads();
  if (tid < 32) {
    const int i = tid >> 1, c = tid & 1;
    float s = bc2[c];
    for (int k = 0; k < 512; k++) s += Rb[i][k] * Wc2[k * 2 + c];
    out[i * 2 + c] = s;
  }
}

// ---------------------------------------------------------------------------
extern "C" void kernel_launch(void* const* d_in, const int* in_sizes, int n_in,
                              void* d_out, int out_size, void* d_ws,
                              size_t ws_size, hipStream_t stream) {
  const float* x   = (const float*)d_in[0];
  const float* W1  = (const float*)d_in[1];
  const float* b1  = (const float*)d_in[2];
  const float* g1  = (const float*)d_in[3];
  const float* be1 = (const float*)d_in[4];
  const float* W2  = (const float*)d_in[5];
  const float* b2  = (const float*)d_in[6];
  const float* g2  = (const float*)d_in[7];
  const float* be2 = (const float*)d_in[8];
  const float* Wa1 = (const float*)d_in[9];
  const float* ba1 = (const float*)d_in[10];
  const float* wa2 = (const float*)d_in[11];
  const float* ba2 = (const float*)d_in[12];
  const float* Wc1 = (const float*)d_in[13];
  const float* bc1 = (const float*)d_in[14];
  const float* Wc2 = (const float*)d_in[15];
  const float* bc2 = (const float*)d_in[16];
  float* out = (float*)d_out;

  char* ws = (char*)d_ws;
  __hip_bfloat16* W1T = (__hip_bfloat16*)(ws + 0);          // 1 MB
  __hip_bfloat16* W2T = (__hip_bfloat16*)(ws + 1048576);    // 512 KB
  __hip_bfloat16* WaT = (__hip_bfloat16*)(ws + 1572864);    // 512 KB
  float* scores = (float*)(ws + 2097152);                   // 256 KB
  float* attn   = (float*)(ws + 2359296);                   // 256 KB
  float* part   = (float*)(ws + 2621440);                   // 256 KB
  float* pooled = (float*)(ws + 2883584);                   // 32 KB
  __hip_bfloat16* hbuf = (__hip_bfloat16*)(ws + 4194304);   // 64 MB

  transpose_cast<<<dim3(16, 32), dim3(32, 8), 0, stream>>>(W1, W1T, DDIM, HDIM);
  transpose_cast<<<dim3(16, 16), dim3(32, 8), 0, stream>>>(W2, W2T, HDIM, HDIM);
  transpose_cast<<<dim3(16, 16), dim3(32, 8), 0, stream>>>(Wa1, WaT, HDIM, HDIM);

  gemm_fused<DDIM, true, 0><<<MTOT / BM, 512, 0, stream>>>(
      x, W1T, b1, g1, be1, nullptr, nullptr, hbuf, nullptr);
  gemm_fused<HDIM, false, 0><<<MTOT / BM, 512, 0, stream>>>(
      hbuf, W2T, b2, g2, be2, nullptr, nullptr, hbuf, nullptr);
  gemm_fused<HDIM, false, 1><<<MTOT / BM, 512, 0, stream>>>(
      hbuf, WaT, ba1, nullptr, nullptr, wa2, ba2, nullptr, scores);

  softmax_bag<<<NBAG, 256, 0, stream>>>(scores, attn);
  pooled_partial<<<512, 256, 0, stream>>>(hbuf, attn, part);
  pooled_reduce<<<32, 256, 0, stream>>>(part, pooled);
  classifier<<<1, 512, 0, stream>>>(pooled, Wc1, bc1, Wc2, bc2, out);
}